// Round 18
// baseline (132.853 us; speedup 1.0000x reference)
//
#include <hip/hip_runtime.h>

#define HD 14
#define NOUT 2
#define NN 200000
#define EE 3200000
#define GG 2000

// bucket config
#define WNODE 64                          // nodes per bucket (c >> 6)
#define NBIN 3125                         // 200000 / 64 exactly
#define NBINP 3200                        // padded row stride for ghist (ints)
#define NBLKA 256                         // partition blocks
#define EPERA 12500                       // edges per partition block
#define NCELL (NBIN*NBLKA)                // 800000
#define TILE 1024                         // edges per in-block sort tile

// scan config
#define SBS 256
#define SEL 8
#define CHUNK (SBS*SEL)                   // 2048
#define NBSCAN ((NCELL + CHUNK - 1) / CHUNK)  // 391

typedef __fp16 hv2 __attribute__((ext_vector_type(2)));
union HU { hv2 h; __fp16 f[2]; unsigned u; int i; };
__device__ __forceinline__ hv2 as_h2(unsigned u) { HU x; x.u = u; return x.h; }

__device__ __forceinline__ float psi_f(float v) {
    float r = __logf(1.0f + fabsf(v));
    return __builtin_copysignf(r, v);
}

__device__ __forceinline__ int lower_bound_i(const int* a, int n, int key) {
    int lo = 0, hi = n;
    while (lo < hi) { int mid = (lo + hi) >> 1; if (a[mid] < key) lo = mid + 1; else hi = mid; }
    return lo;
}

// ---- pass 0: fold We2 into Wn11; emit f16-packed weight pairs ----
__global__ void __launch_bounds__(256)
fold_kernel(const float* __restrict__ We1,
            const float* __restrict__ We2, const float* __restrict__ be2,
            const float* __restrict__ Wn11, const float* __restrict__ bn11,
            float* __restrict__ bp, unsigned* __restrict__ We1pk,
            unsigned* __restrict__ Cpk)
{
    __shared__ float sC[HD*HD];
    int t = threadIdx.x;
    if (t < HD*HD) {
        int k = t / HD, j = t % HD;
        float s = 0.f;
        #pragma unroll
        for (int u = 0; u < HD; ++u) s = fmaf(We2[k*HD+u], Wn11[(1+u)*HD+j], s);
        sC[t] = s;
    } else if (t < HD*HD + HD) {
        int j = t - HD*HD;
        float s = bn11[j];
        #pragma unroll
        for (int u = 0; u < HD; ++u) s = fmaf(be2[u], Wn11[(1+u)*HD+j], s);
        bp[j] = s;
    }
    __syncthreads();
    if (t < 7*HD) {                      // Cpk[tt*14+j] = pack(C[2tt][j], C[2tt+1][j])
        int tt = t / HD, j = t % HD;
        HU x; x.h = __builtin_amdgcn_cvt_pkrtz(sC[(2*tt)*HD + j], sC[(2*tt+1)*HD + j]);
        Cpk[t] = x.u;
    } else if (t < 7*HD + 2*HD) {        // We1pk[tt*14+j] = pack(We1[2tt][j], We1[2tt+1][j])
        int q = t - 7*HD;
        int tt = q / HD, j = q % HD;
        HU x; x.h = __builtin_amdgcn_cvt_pkrtz(We1[(2*tt)*HD + j], We1[(2*tt+1)*HD + j]);
        We1pk[q] = x.u;
    }
}

// ---- pass 1: per-(bucket, block) histogram of col>>6, row-major output ----
__global__ void __launch_bounds__(1024)
histA(const int* __restrict__ col, int* __restrict__ ghist)
{
    __shared__ int hist[NBIN];
    int tid = threadIdx.x;
    for (int i = tid; i < NBIN; i += 1024) hist[i] = 0;
    __syncthreads();
    int j = blockIdx.x;
    int base = j * EPERA;
    for (int it = 0; it < EPERA; it += 1024) {
        int o = it + tid;
        if (o < EPERA) atomicAdd(&hist[col[base + o] >> 6], 1);
    }
    __syncthreads();
    for (int i = tid; i < NBIN; i += 1024) ghist[j * NBINP + i] = hist[i];
}

// ---- scan over bin-major cell order; reads ghist via transpose gather ----
// cell c = bin*NBLKA + j  ->  ghist[(c & 255) * NBINP + (c >> 8)]
__global__ void __launch_bounds__(SBS)
scan1_kernel(const int* __restrict__ ghist, int* __restrict__ excl,
             int* __restrict__ btot, int n)
{
    __shared__ int lds[SBS];
    int tid = threadIdx.x;
    int base = blockIdx.x * CHUNK + tid * SEL;
    int v[SEL]; int s = 0;
    #pragma unroll
    for (int k = 0; k < SEL; ++k) {
        int i = base + k;
        v[k] = (i < n) ? ghist[(i & (NBLKA-1)) * NBINP + (i >> 8)] : 0;
        s += v[k];
    }
    lds[tid] = s; __syncthreads();
    for (int off = 1; off < SBS; off <<= 1) {
        int t = (tid >= off) ? lds[tid - off] : 0;
        __syncthreads();
        lds[tid] += t;
        __syncthreads();
    }
    int incl = lds[tid];
    int run = incl - s;
    if (tid == SBS - 1) btot[blockIdx.x] = incl;
    #pragma unroll
    for (int k = 0; k < SEL; ++k) { int i = base + k; if (i < n) excl[i] = run; run += v[k]; }
}

__global__ void __launch_bounds__(512)
scan2_kernel(int* __restrict__ btot, int nb)
{
    __shared__ int lds[512];
    int tid = threadIdx.x;
    int v = (tid < nb) ? btot[tid] : 0;
    lds[tid] = v; __syncthreads();
    for (int off = 1; off < 512; off <<= 1) {
        int t = (tid >= off) ? lds[tid - off] : 0;
        __syncthreads();
        lds[tid] += t;
        __syncthreads();
    }
    if (tid < nb) btot[tid] = lds[tid] - v;   // exclusive chunk bases, in place
}

// ---- pass 2: partition via LDS staging; coalesced global writeout ----
// 4 bins/thread; hierarchical scan (wave shfl + 16 partials): 2 barriers.
__global__ void __launch_bounds__(1024)
scatterA(const int* __restrict__ row, const int* __restrict__ col,
         const int* __restrict__ ghist,
         const int* __restrict__ excl, const int* __restrict__ btot,
         int* __restrict__ srcdst)
{
    __shared__ int lofs[NBIN + 1];
    __shared__ int cursor[NBIN + 1];
    __shared__ int delta[NBIN + 1];
    __shared__ int wpart[16];
    __shared__ int lval[EPERA];
    __shared__ int ldel[EPERA];

    int tid = threadIdx.x;
    int lane = tid & 63;
    int wv = tid >> 6;
    int j = blockIdx.x;

    // (a) read this block's counts (coalesced row of ghist); 4 bins/thread
    int cb[4]; int s = 0;
    #pragma unroll
    for (int k = 0; k < 4; ++k) {
        int b = 4 * tid + k;
        cb[k] = (b < NBIN) ? ghist[j * NBINP + b] : 0;
        s += cb[k];
    }

    // wave-level inclusive scan (no barriers)
    int incl = s;
    #pragma unroll
    for (int st = 1; st < 64; st <<= 1) {
        int t = __shfl_up(incl, st, 64);
        if (lane >= st) incl += t;
    }
    if (lane == 63) wpart[wv] = incl;
    __syncthreads();

    // wave 0 scans the 16 wave totals (exclusive)
    if (wv == 0 && lane < 16) {
        int v = wpart[lane];
        int iv = v;
        #pragma unroll
        for (int st = 1; st < 16; st <<= 1) {
            int t = __shfl_up(iv, st, 16);
            if ((lane & 15) >= st) iv += t;
        }
        wpart[lane] = iv - v;
    }
    __syncthreads();

    int base = wpart[wv] + incl - s;          // exclusive base for this thread
    #pragma unroll
    for (int k = 0; k < 4; ++k) {
        int b = 4 * tid + k;
        if (b <= NBIN) { lofs[b] = base; cursor[b] = base; }
        base += cb[k];
    }
    __syncthreads();

    // (b) delta[bin] = global cell base - local offset
    for (int b = tid; b < NBIN; b += 1024) {
        int cell = b * NBLKA + j;
        delta[b] = excl[cell] + btot[cell >> 11] - lofs[b];
    }
    __syncthreads();

    // (c) rank into LDS staging
    int ebase = j * EPERA;
    for (int o = tid; o < EPERA; o += 1024) {
        int e = ebase + o;
        int c = col[e];
        int r = row[e];
        int bin = c >> 6;
        int dl = c & 63;
        int pos = atomicAdd(&cursor[bin], 1);
        lval[pos] = r | (dl << 18);
        ldel[pos] = delta[bin];
    }
    __syncthreads();

    // (d) coalesced writeout
    for (int o = tid; o < EPERA; o += 1024) {
        srcdst[o + ldel[o]] = lval[o];
    }
}

// ---- pass 3: per-bucket tile counting-sort + edge-parallel fdot2 compute +
//              f16-packed shfl wave-segmented reduction (r15 structure,
//              WNODE=64 for grid-occupancy; per-edge pipeline frozen) ----
__global__ void __launch_bounds__(256)
bucket_kernel(const float4* __restrict__ x,
              const int* __restrict__ srcdst,
              const int* __restrict__ excl, const int* __restrict__ btot,
              const unsigned* __restrict__ We1pk, const float* __restrict__ be1,
              const float* __restrict__ Wn11,    // row 0 used
              const unsigned* __restrict__ Cpk, const float* __restrict__ bp,
              const float* __restrict__ Wn12, const float* __restrict__ bn12,
              const float* __restrict__ Wn21, const float* __restrict__ bn21,
              const float* __restrict__ Wn22, const float* __restrict__ bn22,
              float* __restrict__ x_out, int N, int E)
{
    __shared__ float4 xn[WNODE];
    __shared__ float nf2[WNODE];
    __shared__ float aggs[WNODE * 15];
    __shared__ int hist[WNODE];
    __shared__ int cursor[WNODE];
    __shared__ int degs[WNODE];
    __shared__ int sorted[TILE];

    int tid = threadIdx.x;
    int lane = tid & 63;
    int wv = tid >> 6;

    int b = blockIdx.x;
    int nb0 = b * WNODE;
    int nN = min(WNODE, N - nb0);

    if (tid < WNODE) degs[tid] = 0;
    for (int i = tid; i < WNODE * 15; i += 256) aggs[i] = 0.f;

    if (tid < nN) {
        float4 v = x[nb0 + tid];
        xn[tid] = v;
        nf2[tid] = psi_f(-v.x*v.x + v.y*v.y + v.z*v.z + v.w*v.w);
    }

    int c0 = b * NBLKA;
    int lo = excl[c0] + btot[c0 >> 11];
    int hi;
    if (b + 1 < NBIN) { int c1 = (b + 1) * NBLKA; hi = excl[c1] + btot[c1 >> 11]; }
    else hi = E;

    __syncthreads();

    for (int tb = lo; tb < hi; tb += TILE) {
        int tsz = min(TILE, hi - tb);

        if (tid < WNODE) hist[tid] = 0;
        __syncthreads();

        // count
        for (int o = tid; o < tsz; o += 256) {
            int p = srcdst[tb + o];
            atomicAdd(&hist[p >> 18], 1);
        }
        __syncthreads();

        // wave-synchronous exclusive scan of 64 bins by wave 0 (1 bin/lane)
        if (wv == 0) {
            int a0 = hist[lane];
            int s = a0;
            #pragma unroll
            for (int st = 1; st < 64; st <<= 1) {
                int t = __shfl_up(s, st, 64);
                if (lane >= st) s += t;
            }
            cursor[lane] = s - a0;
            degs[lane] += a0;
        }
        __syncthreads();

        // scatter into sorted[]
        for (int o = tid; o < tsz; o += 256) {
            int p = srcdst[tb + o];
            int pos = atomicAdd(&cursor[p >> 18], 1);
            sorted[pos] = p;
        }
        __syncthreads();

        // edge-parallel compute + packed-f16 shfl segmented reduction
        for (int cb = wv * 64; cb < tsz; cb += 256) {
            int o = cb + lane;
            bool valid = (o < tsz);
            int p = valid ? sorted[o] : 0;
            int nid = valid ? (p >> 18) : WNODE;          // sentinel for tail lanes

            hv2 h2p[7];
            HU uz; uz.u = 0;
            #pragma unroll
            for (int t = 0; t < 7; ++t) h2p[t] = uz.h;

            if (valid) {
                float4 a = x[p & 262143];
                float4 bx = xn[nid];
                float f2 = nf2[nid];

                float f0 = -a.x*a.x + a.y*a.y + a.z*a.z + a.w*a.w;
                float f1 = -a.x*bx.x + a.y*bx.y + a.z*bx.z + a.w*bx.w;
                float dx = a.x-bx.x, dy = a.y-bx.y, dz = a.z-bx.z, dw = a.w-bx.w;
                float f3 = psi_f(-dx*dx + dy*dy + dz*dz + dw*dw);

                hv2 f01 = __builtin_amdgcn_cvt_pkrtz(f0, f1);
                hv2 f23 = __builtin_amdgcn_cvt_pkrtz(f2, f3);

                float h1[HD];
                #pragma unroll
                for (int j = 0; j < HD; ++j) {
                    float v = __builtin_amdgcn_fdot2(f23, as_h2(We1pk[HD + j]), be1[j], false);
                    v = __builtin_amdgcn_fdot2(f01, as_h2(We1pk[j]), v, false);
                    h1[j] = fmaxf(v, 0.f);
                }
                hv2 h1p[7];
                #pragma unroll
                for (int t = 0; t < 7; ++t) h1p[t] = __builtin_amdgcn_cvt_pkrtz(h1[2*t], h1[2*t+1]);

                float h2[HD];
                #pragma unroll
                for (int j = 0; j < HD; ++j) {
                    float v = fmaf(f0, Wn11[j], bp[j]);
                    #pragma unroll
                    for (int t = 0; t < 7; ++t) v = __builtin_amdgcn_fdot2(h1p[t], as_h2(Cpk[t*HD + j]), v, false);
                    h2[j] = fmaxf(v, 0.f);
                }
                #pragma unroll
                for (int t = 0; t < 7; ++t) h2p[t] = __builtin_amdgcn_cvt_pkrtz(h2[2*t], h2[2*t+1]);
            }

            // segmented inclusive sum over non-decreasing nid (packed f16 pairs)
            #pragma unroll
            for (int st = 1; st < 64; st <<= 1) {
                int nup = __shfl_up(nid, st, 64);
                bool take = (lane >= st) && (nup == nid);
                #pragma unroll
                for (int t = 0; t < 7; ++t) {
                    HU u; u.h = h2p[t];
                    u.i = __shfl_up(u.i, st, 64);
                    if (take) h2p[t] += u.h;
                }
            }
            int ndn = __shfl_down(nid, 1, 64);
            bool lastseg = valid && (lane == 63 || ndn != nid);
            if (lastseg) {
                #pragma unroll
                for (int t = 0; t < 7; ++t) {
                    HU u; u.h = h2p[t];
                    atomicAdd(&aggs[nid * 15 + 2*t],     (float)u.f[0]);
                    atomicAdd(&aggs[nid * 15 + 2*t + 1], (float)u.f[1]);
                }
            }
        }
        __syncthreads();
    }

    // finalize node tid (scalar-pipe f32 weights)
    if (tid < nN) {
        int deg = degs[tid];
        float aggm[HD];
        if (deg > 0) {
            float inv = 1.0f / (float)deg;
            float am[HD];
            #pragma unroll
            for (int k = 0; k < HD; ++k) am[k] = aggs[tid * 15 + k] * inv;
            #pragma unroll
            for (int j = 0; j < HD; ++j) {
                float v = bn12[j];
                #pragma unroll
                for (int k = 0; k < HD; ++k) v = fmaf(am[k], Wn12[k*HD+j], v);
                aggm[j] = v;
            }
        } else {
            #pragma unroll
            for (int j = 0; j < HD; ++j) aggm[j] = 0.f;
        }

        float4 v4 = xn[tid];
        float ipbb = -v4.x*v4.x + v4.y*v4.y + v4.z*v4.z + v4.w*v4.w;
        float h[HD];
        #pragma unroll
        for (int j = 0; j < HD; ++j) {
            float v = fmaf(ipbb, Wn21[j], bn21[j]);
            #pragma unroll
            for (int k = 0; k < HD; ++k) v = fmaf(aggm[k], Wn21[(1+k)*HD+j], v);
            h[j] = fmaxf(v, 0.f);
        }
        float xo[16];
        #pragma unroll
        for (int j = 0; j < HD; ++j) {
            float v = bn22[j];
            #pragma unroll
            for (int k = 0; k < HD; ++k) v = fmaf(h[k], Wn22[k*HD+j], v);
            xo[j] = v;
        }
        float4* op = (float4*)(x_out + (size_t)(nb0 + tid) * 16);
        op[0] = make_float4(xo[0], xo[1], xo[2], xo[3]);
        op[1] = make_float4(xo[4], xo[5], xo[6], xo[7]);
        op[2] = make_float4(xo[8], xo[9], xo[10], xo[11]);
        op[3] = make_float4(xo[12], xo[13], 0.f, 0.f);
    }
}

// ---- pass 4: per-graph mean + global MLP ----
__global__ void __launch_bounds__(256)
graph_kernel(const float* __restrict__ x_out, const int* __restrict__ batch,
             const float* __restrict__ Wg1, const float* __restrict__ bg1,
             const float* __restrict__ Wg2, const float* __restrict__ bg2,
             float* __restrict__ out, int N, int G)
{
    __shared__ float red[256 * 15];
    int g = blockIdx.x;
    int tid = threadIdx.x;

    int lo = lower_bound_i(batch, N, g);
    int hi = lower_bound_i(batch, N, g + 1);

    float acc[HD];
    #pragma unroll
    for (int j = 0; j < HD; ++j) acc[j] = 0.f;

    for (int n = lo + tid; n < hi; n += 256) {
        const float* xp = x_out + (size_t)n * 16;
        #pragma unroll
        for (int j = 0; j < HD; ++j) acc[j] += xp[j];
    }
    #pragma unroll
    for (int j = 0; j < HD; ++j) red[tid * 15 + j] = acc[j];
    __syncthreads();

    for (int s = 128; s >= 1; s >>= 1) {
        if (tid < s) {
            #pragma unroll
            for (int j = 0; j < HD; ++j) red[tid * 15 + j] += red[(tid + s) * 15 + j];
        }
        __syncthreads();
    }

    if (tid == 0) {
        float invc = 1.0f / fmaxf((float)(hi - lo), 1.0f);
        float gm[HD];
        #pragma unroll
        for (int j = 0; j < HD; ++j) gm[j] = red[j] * invc;
        float h[HD];
        #pragma unroll
        for (int j = 0; j < HD; ++j) {
            float v = bg1[j];
            #pragma unroll
            for (int k = 0; k < HD; ++k) v = fmaf(gm[k], Wg1[k*HD+j], v);
            h[j] = fmaxf(v, 0.f);
        }
        #pragma unroll
        for (int o = 0; o < NOUT; ++o) {
            float v = bg2[o];
            #pragma unroll
            for (int k = 0; k < HD; ++k) v = fmaf(h[k], Wg2[k*NOUT+o], v);
            out[g * NOUT + o] = v;
        }
    }
}

extern "C" void kernel_launch(void* const* d_in, const int* in_sizes, int n_in,
                              void* d_out, int out_size, void* d_ws, size_t ws_size,
                              hipStream_t stream) {
    const int N = NN, E = EE, G = GG;

    const float4* x     = (const float4*)d_in[0];
    const int*    eidx  = (const int*)d_in[1];
    const int*    batch = (const int*)d_in[2];
    const float*  We1  = (const float*)d_in[3];
    const float*  be1  = (const float*)d_in[4];
    const float*  We2  = (const float*)d_in[5];
    const float*  be2  = (const float*)d_in[6];
    const float*  Wn11 = (const float*)d_in[7];
    const float*  bn11 = (const float*)d_in[8];
    const float*  Wn12 = (const float*)d_in[9];
    const float*  bn12 = (const float*)d_in[10];
    const float*  Wn21 = (const float*)d_in[11];
    const float*  bn21 = (const float*)d_in[12];
    const float*  Wn22 = (const float*)d_in[13];
    const float*  bn22 = (const float*)d_in[14];
    const float*  Wg1  = (const float*)d_in[15];
    const float*  bg1  = (const float*)d_in[16];
    const float*  Wg2  = (const float*)d_in[17];
    const float*  bg2  = (const float*)d_in[18];

    const int* row = eidx;       // edge_index[0]
    const int* col = eidx + E;   // edge_index[1]

    // workspace layout (bytes) — every buffer fully written before read, no memsets:
    //   ghist  @ 0          NBLKA*NBINP ints (3,276,800) row-major [j][bin]
    //   excl   @ 4,194,304  NCELL ints  (3,200,000) bin-major
    //   btot   @ 7,394,304  NBSCAN ints (1,564)
    //   bfold  @ 7,395,968  (56)
    //   We1pk  @ 7,396,224  (112)
    //   Cpk    @ 7,396,480  (392)
    //   srcdst @ 8,388,608  E ints      (12,800,000) -> ends 21,188,608
    //   x_out  @ 21,188,608 N*16 floats (12,800,000) -> ends 33,988,608
    char*     ws     = (char*)d_ws;
    int*      ghist  = (int*)(ws + 0);
    int*      excl   = (int*)(ws + 4194304);
    int*      btot   = (int*)(ws + 7394304);
    float*    bfold  = (float*)(ws + 7395968);
    unsigned* We1pk  = (unsigned*)(ws + 7396224);
    unsigned* Cpk    = (unsigned*)(ws + 7396480);
    int*      srcdst = (int*)(ws + 8388608);
    float*    x_out  = (float*)(ws + 21188608);

    dim3 blk(256);
    fold_kernel<<<dim3(1), blk, 0, stream>>>(We1, We2, be2, Wn11, bn11,
                                             bfold, We1pk, Cpk);

    histA<<<dim3(NBLKA), dim3(1024), 0, stream>>>(col, ghist);
    scan1_kernel<<<dim3(NBSCAN), dim3(SBS), 0, stream>>>(ghist, excl, btot, NCELL);
    scan2_kernel<<<dim3(1), dim3(512), 0, stream>>>(btot, NBSCAN);
    scatterA<<<dim3(NBLKA), dim3(1024), 0, stream>>>(row, col, ghist, excl, btot, srcdst);

    bucket_kernel<<<dim3(NBIN), blk, 0, stream>>>(
        x, srcdst, excl, btot,
        We1pk, be1, Wn11, Cpk, bfold,
        Wn12, bn12, Wn21, bn21, Wn22, bn22,
        x_out, N, E);

    graph_kernel<<<dim3(G), blk, 0, stream>>>(x_out, batch, Wg1, bg1, Wg2, bg2,
                                              (float*)d_out, N, G);
}

// Round 19
// 129.332 us; speedup vs baseline: 1.0272x; 1.0272x over previous
//
#include <hip/hip_runtime.h>

#define HD 14
#define NOUT 2
#define NN 200000
#define EE 3200000
#define GG 2000

// bucket config
#define WNODE 128                         // nodes per bucket (c >> 7)
#define NBIN 1563                         // ceil(200000/128)
#define NBINP 1600                        // padded row stride for ghist (ints)
#define NBLKA 256                         // partition blocks
#define EPERA 12500                       // edges per partition block
#define NCELL (NBIN*NBLKA)                // 400128
#define TILE 2048                         // edges per in-block sort tile

// scan config
#define SBS 256
#define SEL 8
#define CHUNK (SBS*SEL)                   // 2048
#define NBSCAN ((NCELL + CHUNK - 1) / CHUNK)  // 196

typedef __fp16 hv2 __attribute__((ext_vector_type(2)));
union HU { hv2 h; __fp16 f[2]; unsigned u; int i; };
__device__ __forceinline__ hv2 as_h2(unsigned u) { HU x; x.u = u; return x.h; }

__device__ __forceinline__ float psi_f(float v) {
    float r = __logf(1.0f + fabsf(v));
    return __builtin_copysignf(r, v);
}

__device__ __forceinline__ int lower_bound_i(const int* a, int n, int key) {
    int lo = 0, hi = n;
    while (lo < hi) { int mid = (lo + hi) >> 1; if (a[mid] < key) lo = mid + 1; else hi = mid; }
    return lo;
}

// ---- pass 0: fold We2 into Wn11; emit f16-packed weight pairs ----
__global__ void __launch_bounds__(256)
fold_kernel(const float* __restrict__ We1,
            const float* __restrict__ We2, const float* __restrict__ be2,
            const float* __restrict__ Wn11, const float* __restrict__ bn11,
            float* __restrict__ bp, unsigned* __restrict__ We1pk,
            unsigned* __restrict__ Cpk)
{
    __shared__ float sC[HD*HD];
    int t = threadIdx.x;
    if (t < HD*HD) {
        int k = t / HD, j = t % HD;
        float s = 0.f;
        #pragma unroll
        for (int u = 0; u < HD; ++u) s = fmaf(We2[k*HD+u], Wn11[(1+u)*HD+j], s);
        sC[t] = s;
    } else if (t < HD*HD + HD) {
        int j = t - HD*HD;
        float s = bn11[j];
        #pragma unroll
        for (int u = 0; u < HD; ++u) s = fmaf(be2[u], Wn11[(1+u)*HD+j], s);
        bp[j] = s;
    }
    __syncthreads();
    if (t < 7*HD) {                      // Cpk[tt*14+j] = pack(C[2tt][j], C[2tt+1][j])
        int tt = t / HD, j = t % HD;
        HU x; x.h = __builtin_amdgcn_cvt_pkrtz(sC[(2*tt)*HD + j], sC[(2*tt+1)*HD + j]);
        Cpk[t] = x.u;
    } else if (t < 7*HD + 2*HD) {        // We1pk[tt*14+j] = pack(We1[2tt][j], We1[2tt+1][j])
        int q = t - 7*HD;
        int tt = q / HD, j = q % HD;
        HU x; x.h = __builtin_amdgcn_cvt_pkrtz(We1[(2*tt)*HD + j], We1[(2*tt+1)*HD + j]);
        We1pk[q] = x.u;
    }
}

// ---- pass 1: per-(bucket, block) histogram of col>>7 ----
// Row-major output ghist[j][bin] -> fully coalesced writes (no cross-block
// line sharing / write-allocate RMW).
__global__ void __launch_bounds__(1024)
histA(const int* __restrict__ col, int* __restrict__ ghist)
{
    __shared__ int hist[NBIN];
    int tid = threadIdx.x;
    for (int i = tid; i < NBIN; i += 1024) hist[i] = 0;
    __syncthreads();
    int j = blockIdx.x;
    int base = j * EPERA;
    for (int it = 0; it < EPERA; it += 1024) {
        int o = it + tid;
        if (o < EPERA) atomicAdd(&hist[col[base + o] >> 7], 1);
    }
    __syncthreads();
    for (int i = tid; i < NBIN; i += 1024) ghist[j * NBINP + i] = hist[i];
}

// ---- scan over bin-major cell order; reads ghist via transpose gather ----
// cell c = bin*NBLKA + j  ->  ghist[(c & 255) * NBINP + (c >> 8)]
__global__ void __launch_bounds__(SBS)
scan1_kernel(const int* __restrict__ ghist, int* __restrict__ excl,
             int* __restrict__ btot, int n)
{
    __shared__ int lds[SBS];
    int tid = threadIdx.x;
    int base = blockIdx.x * CHUNK + tid * SEL;
    int v[SEL]; int s = 0;
    #pragma unroll
    for (int k = 0; k < SEL; ++k) {
        int i = base + k;
        v[k] = (i < n) ? ghist[(i & (NBLKA-1)) * NBINP + (i >> 8)] : 0;
        s += v[k];
    }
    lds[tid] = s; __syncthreads();
    for (int off = 1; off < SBS; off <<= 1) {
        int t = (tid >= off) ? lds[tid - off] : 0;
        __syncthreads();
        lds[tid] += t;
        __syncthreads();
    }
    int incl = lds[tid];
    int run = incl - s;
    if (tid == SBS - 1) btot[blockIdx.x] = incl;
    #pragma unroll
    for (int k = 0; k < SEL; ++k) { int i = base + k; if (i < n) excl[i] = run; run += v[k]; }
}

__global__ void __launch_bounds__(256)
scan2_kernel(int* __restrict__ btot, int nb)
{
    __shared__ int lds[256];
    int tid = threadIdx.x;
    int v = (tid < nb) ? btot[tid] : 0;
    lds[tid] = v; __syncthreads();
    for (int off = 1; off < 256; off <<= 1) {
        int t = (tid >= off) ? lds[tid - off] : 0;
        __syncthreads();
        lds[tid] += t;
        __syncthreads();
    }
    if (tid < nb) btot[tid] = lds[tid] - v;   // exclusive chunk bases, in place
}

// ---- pass 2: partition via LDS staging; coalesced global writeout ----
// Bin-count scan done hierarchically (wave shfl + 16 partials): 2 barriers
// instead of 20.
__global__ void __launch_bounds__(1024)
scatterA(const int* __restrict__ row, const int* __restrict__ col,
         const int* __restrict__ ghist,
         const int* __restrict__ excl, const int* __restrict__ btot,
         int* __restrict__ srcdst)
{
    __shared__ int lofs[NBIN + 1];
    __shared__ int cursor[NBIN + 1];
    __shared__ int delta[NBIN + 1];
    __shared__ int wpart[16];
    __shared__ int lval[EPERA];
    __shared__ int ldel[EPERA];

    int tid = threadIdx.x;
    int lane = tid & 63;
    int wv = tid >> 6;
    int j = blockIdx.x;

    // (a) read this block's counts (coalesced row of ghist); 2 bins/thread
    int b0 = 2 * tid, b1 = 2 * tid + 1;
    int c0 = (b0 < NBIN) ? ghist[j * NBINP + b0] : 0;
    int c1 = (b1 < NBIN) ? ghist[j * NBINP + b1] : 0;
    int s = c0 + c1;

    // wave-level inclusive scan (no barriers)
    int incl = s;
    #pragma unroll
    for (int st = 1; st < 64; st <<= 1) {
        int t = __shfl_up(incl, st, 64);
        if (lane >= st) incl += t;
    }
    if (lane == 63) wpart[wv] = incl;
    __syncthreads();

    // wave 0 scans the 16 wave totals (exclusive)
    if (wv == 0 && lane < 16) {
        int v = wpart[lane];
        int iv = v;
        #pragma unroll
        for (int st = 1; st < 16; st <<= 1) {
            int t = __shfl_up(iv, st, 16);
            if ((lane & 15) >= st) iv += t;
        }
        wpart[lane] = iv - v;
    }
    __syncthreads();

    int base = wpart[wv] + incl - s;          // exclusive base for this thread
    if (b0 <= NBIN) { lofs[b0] = base; cursor[b0] = base; }
    if (b1 <= NBIN) { lofs[b1] = base + c0; cursor[b1] = base + c0; }
    __syncthreads();

    // (b) delta[bin] = global cell base - local offset
    for (int b = tid; b < NBIN; b += 1024) {
        int cell = b * NBLKA + j;
        delta[b] = excl[cell] + btot[cell >> 11] - lofs[b];
    }
    __syncthreads();

    // (c) rank into LDS staging
    int ebase = j * EPERA;
    for (int o = tid; o < EPERA; o += 1024) {
        int e = ebase + o;
        int c = col[e];
        int r = row[e];
        int bin = c >> 7;
        int dl = c & 127;
        int pos = atomicAdd(&cursor[bin], 1);
        lval[pos] = r | (dl << 18);
        ldel[pos] = delta[bin];
    }
    __syncthreads();

    // (d) coalesced writeout
    for (int o = tid; o < EPERA; o += 1024) {
        srcdst[o + ldel[o]] = lval[o];
    }
}

// ---- pass 3: per-bucket tile counting-sort + edge-parallel fdot2 compute +
//              f16-packed shfl wave-segmented reduction (r15 proven, frozen) ----
__global__ void __launch_bounds__(256)
bucket_kernel(const float4* __restrict__ x,
              const int* __restrict__ srcdst,
              const int* __restrict__ excl, const int* __restrict__ btot,
              const unsigned* __restrict__ We1pk, const float* __restrict__ be1,
              const float* __restrict__ Wn11,    // row 0 used
              const unsigned* __restrict__ Cpk, const float* __restrict__ bp,
              const float* __restrict__ Wn12, const float* __restrict__ bn12,
              const float* __restrict__ Wn21, const float* __restrict__ bn21,
              const float* __restrict__ Wn22, const float* __restrict__ bn22,
              float* __restrict__ x_out, int N, int E)
{
    __shared__ float4 xn[WNODE];
    __shared__ float nf2[WNODE];
    __shared__ float aggs[WNODE * 15];
    __shared__ int hist[WNODE];
    __shared__ int cursor[WNODE];
    __shared__ int degs[WNODE];
    __shared__ int sorted[TILE];

    int tid = threadIdx.x;
    int lane = tid & 63;
    int wv = tid >> 6;

    int b = blockIdx.x;
    int nb0 = b * WNODE;
    int nN = min(WNODE, N - nb0);

    if (tid < WNODE) degs[tid] = 0;
    for (int i = tid; i < WNODE * 15; i += 256) aggs[i] = 0.f;

    if (tid < nN) {
        float4 v = x[nb0 + tid];
        xn[tid] = v;
        nf2[tid] = psi_f(-v.x*v.x + v.y*v.y + v.z*v.z + v.w*v.w);
    }

    int c0 = b * NBLKA;
    int lo = excl[c0] + btot[c0 >> 11];
    int hi;
    if (b + 1 < NBIN) { int c1 = (b + 1) * NBLKA; hi = excl[c1] + btot[c1 >> 11]; }
    else hi = E;

    __syncthreads();

    for (int tb = lo; tb < hi; tb += TILE) {
        int tsz = min(TILE, hi - tb);

        if (tid < WNODE) hist[tid] = 0;
        __syncthreads();

        // count
        for (int o = tid; o < tsz; o += 256) {
            int p = srcdst[tb + o];
            atomicAdd(&hist[p >> 18], 1);
        }
        __syncthreads();

        // wave-synchronous exclusive scan of 128 bins by wave 0 (2 bins/lane)
        if (wv == 0) {
            int a0 = hist[2*lane];
            int a1 = hist[2*lane + 1];
            int s = a0 + a1;
            #pragma unroll
            for (int st = 1; st < 64; st <<= 1) {
                int t = __shfl_up(s, st, 64);
                if (lane >= st) s += t;
            }
            int exb = s - (a0 + a1);
            cursor[2*lane]     = exb;
            cursor[2*lane + 1] = exb + a0;
            degs[2*lane]     += a0;
            degs[2*lane + 1] += a1;
        }
        __syncthreads();

        // scatter into sorted[]
        for (int o = tid; o < tsz; o += 256) {
            int p = srcdst[tb + o];
            int pos = atomicAdd(&cursor[p >> 18], 1);
            sorted[pos] = p;
        }
        __syncthreads();

        // edge-parallel compute + packed-f16 shfl segmented reduction
        for (int cb = wv * 64; cb < tsz; cb += 256) {
            int o = cb + lane;
            bool valid = (o < tsz);
            int p = valid ? sorted[o] : 0;
            int nid = valid ? (p >> 18) : WNODE;          // sentinel for tail lanes

            hv2 h2p[7];
            HU uz; uz.u = 0;
            #pragma unroll
            for (int t = 0; t < 7; ++t) h2p[t] = uz.h;

            if (valid) {
                float4 a = x[p & 262143];
                float4 bx = xn[nid];
                float f2 = nf2[nid];

                float f0 = -a.x*a.x + a.y*a.y + a.z*a.z + a.w*a.w;
                float f1 = -a.x*bx.x + a.y*bx.y + a.z*bx.z + a.w*bx.w;
                float dx = a.x-bx.x, dy = a.y-bx.y, dz = a.z-bx.z, dw = a.w-bx.w;
                float f3 = psi_f(-dx*dx + dy*dy + dz*dz + dw*dw);

                hv2 f01 = __builtin_amdgcn_cvt_pkrtz(f0, f1);
                hv2 f23 = __builtin_amdgcn_cvt_pkrtz(f2, f3);

                float h1[HD];
                #pragma unroll
                for (int j = 0; j < HD; ++j) {
                    float v = __builtin_amdgcn_fdot2(f23, as_h2(We1pk[HD + j]), be1[j], false);
                    v = __builtin_amdgcn_fdot2(f01, as_h2(We1pk[j]), v, false);
                    h1[j] = fmaxf(v, 0.f);
                }
                hv2 h1p[7];
                #pragma unroll
                for (int t = 0; t < 7; ++t) h1p[t] = __builtin_amdgcn_cvt_pkrtz(h1[2*t], h1[2*t+1]);

                float h2[HD];
                #pragma unroll
                for (int j = 0; j < HD; ++j) {
                    float v = fmaf(f0, Wn11[j], bp[j]);
                    #pragma unroll
                    for (int t = 0; t < 7; ++t) v = __builtin_amdgcn_fdot2(h1p[t], as_h2(Cpk[t*HD + j]), v, false);
                    h2[j] = fmaxf(v, 0.f);
                }
                #pragma unroll
                for (int t = 0; t < 7; ++t) h2p[t] = __builtin_amdgcn_cvt_pkrtz(h2[2*t], h2[2*t+1]);
            }

            // segmented inclusive sum over non-decreasing nid (packed f16 pairs)
            #pragma unroll
            for (int st = 1; st < 64; st <<= 1) {
                int nup = __shfl_up(nid, st, 64);
                bool take = (lane >= st) && (nup == nid);
                #pragma unroll
                for (int t = 0; t < 7; ++t) {
                    HU u; u.h = h2p[t];
                    u.i = __shfl_up(u.i, st, 64);
                    if (take) h2p[t] += u.h;
                }
            }
            int ndn = __shfl_down(nid, 1, 64);
            bool lastseg = valid && (lane == 63 || ndn != nid);
            if (lastseg) {
                #pragma unroll
                for (int t = 0; t < 7; ++t) {
                    HU u; u.h = h2p[t];
                    atomicAdd(&aggs[nid * 15 + 2*t],     (float)u.f[0]);
                    atomicAdd(&aggs[nid * 15 + 2*t + 1], (float)u.f[1]);
                }
            }
        }
        __syncthreads();
    }

    // finalize node tid (scalar-pipe f32 weights)
    if (tid < nN) {
        int deg = degs[tid];
        float aggm[HD];
        if (deg > 0) {
            float inv = 1.0f / (float)deg;
            float am[HD];
            #pragma unroll
            for (int k = 0; k < HD; ++k) am[k] = aggs[tid * 15 + k] * inv;
            #pragma unroll
            for (int j = 0; j < HD; ++j) {
                float v = bn12[j];
                #pragma unroll
                for (int k = 0; k < HD; ++k) v = fmaf(am[k], Wn12[k*HD+j], v);
                aggm[j] = v;
            }
        } else {
            #pragma unroll
            for (int j = 0; j < HD; ++j) aggm[j] = 0.f;
        }

        float4 v4 = xn[tid];
        float ipbb = -v4.x*v4.x + v4.y*v4.y + v4.z*v4.z + v4.w*v4.w;
        float h[HD];
        #pragma unroll
        for (int j = 0; j < HD; ++j) {
            float v = fmaf(ipbb, Wn21[j], bn21[j]);
            #pragma unroll
            for (int k = 0; k < HD; ++k) v = fmaf(aggm[k], Wn21[(1+k)*HD+j], v);
            h[j] = fmaxf(v, 0.f);
        }
        float xo[16];
        #pragma unroll
        for (int j = 0; j < HD; ++j) {
            float v = bn22[j];
            #pragma unroll
            for (int k = 0; k < HD; ++k) v = fmaf(h[k], Wn22[k*HD+j], v);
            xo[j] = v;
        }
        float4* op = (float4*)(x_out + (size_t)(nb0 + tid) * 16);
        op[0] = make_float4(xo[0], xo[1], xo[2], xo[3]);
        op[1] = make_float4(xo[4], xo[5], xo[6], xo[7]);
        op[2] = make_float4(xo[8], xo[9], xo[10], xo[11]);
        op[3] = make_float4(xo[12], xo[13], 0.f, 0.f);
    }
}

// ---- pass 4: per-graph mean + global MLP ----
__global__ void __launch_bounds__(256)
graph_kernel(const float* __restrict__ x_out, const int* __restrict__ batch,
             const float* __restrict__ Wg1, const float* __restrict__ bg1,
             const float* __restrict__ Wg2, const float* __restrict__ bg2,
             float* __restrict__ out, int N, int G)
{
    __shared__ float red[256 * 15];
    int g = blockIdx.x;
    int tid = threadIdx.x;

    int lo = lower_bound_i(batch, N, g);
    int hi = lower_bound_i(batch, N, g + 1);

    float acc[HD];
    #pragma unroll
    for (int j = 0; j < HD; ++j) acc[j] = 0.f;

    for (int n = lo + tid; n < hi; n += 256) {
        const float* xp = x_out + (size_t)n * 16;
        #pragma unroll
        for (int j = 0; j < HD; ++j) acc[j] += xp[j];
    }
    #pragma unroll
    for (int j = 0; j < HD; ++j) red[tid * 15 + j] = acc[j];
    __syncthreads();

    for (int s = 128; s >= 1; s >>= 1) {
        if (tid < s) {
            #pragma unroll
            for (int j = 0; j < HD; ++j) red[tid * 15 + j] += red[(tid + s) * 15 + j];
        }
        __syncthreads();
    }

    if (tid == 0) {
        float invc = 1.0f / fmaxf((float)(hi - lo), 1.0f);
        float gm[HD];
        #pragma unroll
        for (int j = 0; j < HD; ++j) gm[j] = red[j] * invc;
        float h[HD];
        #pragma unroll
        for (int j = 0; j < HD; ++j) {
            float v = bg1[j];
            #pragma unroll
            for (int k = 0; k < HD; ++k) v = fmaf(gm[k], Wg1[k*HD+j], v);
            h[j] = fmaxf(v, 0.f);
        }
        #pragma unroll
        for (int o = 0; o < NOUT; ++o) {
            float v = bg2[o];
            #pragma unroll
            for (int k = 0; k < HD; ++k) v = fmaf(h[k], Wg2[k*NOUT+o], v);
            out[g * NOUT + o] = v;
        }
    }
}

extern "C" void kernel_launch(void* const* d_in, const int* in_sizes, int n_in,
                              void* d_out, int out_size, void* d_ws, size_t ws_size,
                              hipStream_t stream) {
    const int N = NN, E = EE, G = GG;

    const float4* x     = (const float4*)d_in[0];
    const int*    eidx  = (const int*)d_in[1];
    const int*    batch = (const int*)d_in[2];
    const float*  We1  = (const float*)d_in[3];
    const float*  be1  = (const float*)d_in[4];
    const float*  We2  = (const float*)d_in[5];
    const float*  be2  = (const float*)d_in[6];
    const float*  Wn11 = (const float*)d_in[7];
    const float*  bn11 = (const float*)d_in[8];
    const float*  Wn12 = (const float*)d_in[9];
    const float*  bn12 = (const float*)d_in[10];
    const float*  Wn21 = (const float*)d_in[11];
    const float*  bn21 = (const float*)d_in[12];
    const float*  Wn22 = (const float*)d_in[13];
    const float*  bn22 = (const float*)d_in[14];
    const float*  Wg1  = (const float*)d_in[15];
    const float*  bg1  = (const float*)d_in[16];
    const float*  Wg2  = (const float*)d_in[17];
    const float*  bg2  = (const float*)d_in[18];

    const int* row = eidx;       // edge_index[0]
    const int* col = eidx + E;   // edge_index[1]

    // workspace layout (bytes) — every buffer fully written before read, no memsets:
    //   ghist  @ 0          NBLKA*NBINP ints (1,638,400) row-major [j][bin]
    //   excl   @ 2,097,152  NCELL ints  (1,600,512) bin-major
    //   btot   @ 3,801,088  NBSCAN ints (784)
    //   bfold  @ 3,802,112  (56)
    //   We1pk  @ 3,802,368  (112)
    //   Cpk    @ 3,802,624  (392)
    //   srcdst @ 4,194,304  E ints      (12,800,000) -> ends 16,994,304
    //   x_out  @ 16,994,304 N*16 floats (12,800,000) -> ends 29,794,304
    char*     ws     = (char*)d_ws;
    int*      ghist  = (int*)(ws + 0);
    int*      excl   = (int*)(ws + 2097152);
    int*      btot   = (int*)(ws + 3801088);
    float*    bfold  = (float*)(ws + 3802112);
    unsigned* We1pk  = (unsigned*)(ws + 3802368);
    unsigned* Cpk    = (unsigned*)(ws + 3802624);
    int*      srcdst = (int*)(ws + 4194304);
    float*    x_out  = (float*)(ws + 16994304);

    dim3 blk(256);
    fold_kernel<<<dim3(1), blk, 0, stream>>>(We1, We2, be2, Wn11, bn11,
                                             bfold, We1pk, Cpk);

    histA<<<dim3(NBLKA), dim3(1024), 0, stream>>>(col, ghist);
    scan1_kernel<<<dim3(NBSCAN), dim3(SBS), 0, stream>>>(ghist, excl, btot, NCELL);
    scan2_kernel<<<dim3(1), blk, 0, stream>>>(btot, NBSCAN);
    scatterA<<<dim3(NBLKA), dim3(1024), 0, stream>>>(row, col, ghist, excl, btot, srcdst);

    bucket_kernel<<<dim3(NBIN), blk, 0, stream>>>(
        x, srcdst, excl, btot,
        We1pk, be1, Wn11, Cpk, bfold,
        Wn12, bn12, Wn21, bn21, Wn22, bn22,
        x_out, N, E);

    graph_kernel<<<dim3(G), blk, 0, stream>>>(x_out, batch, Wg1, bg1, Wg2, bg2,
                                              (float*)d_out, N, G);
}